// Round 1
// baseline (3798.486 us; speedup 1.0000x reference)
//
#include <hip/hip_runtime.h>
#include <math.h>

#define NR 8
#define EB 32

__device__ __forceinline__ float silu_f(float x) {
  return x / (1.0f + __expf(-x));
}

// ---------------- node kernel: node_out + v_out ----------------
__global__ __launch_bounds__(128)
void node_kernel(const float* __restrict__ s_t,
                 const float* __restrict__ x_t,
                 const float* __restrict__ v_t,
                 const float* __restrict__ dst_lig_x,
                 const float* __restrict__ dst_lig_a,
                 const float* __restrict__ W1, const float* __restrict__ b1,
                 const float* __restrict__ W2, const float* __restrict__ b2,
                 float* __restrict__ node_out, float* __restrict__ v_out,
                 int N)
{
  __shared__ float in_s[NR][160];   // [rbf 16 | a 16 | s_t 128]
  __shared__ float h_s[NR][128];
  const int j = threadIdx.x;
  const int row0 = blockIdx.x * NR;

  // stage s_t rows (coalesced)
  #pragma unroll
  for (int r = 0; r < NR; ++r) {
    int row = row0 + r;
    if (row < N) in_s[r][32 + j] = s_t[(size_t)row * 128 + j];
  }

  // rbf + dst_lig_a + v_out: 128 threads = 8 rows x 16
  {
    const int r = j >> 4, m = j & 15;
    const int row = row0 + r;
    if (row < N) {
      float ax = x_t[row*3+0], ay = x_t[row*3+1], az = x_t[row*3+2];
      float dx = dst_lig_x[row*3+0] - ax;
      float dy = dst_lig_x[row*3+1] - ay;
      float dz = dst_lig_x[row*3+2] - az;
      float d2 = fmaxf(dx*dx + dy*dy + dz*dz, 1e-8f);
      float dij = sqrtf(d2);
      // mu_m = m * 10/15, sigma = 10/16 -> 1/sigma = 1.6
      float tt = (dij - 0.66666667f * (float)m) * 1.6f;
      in_s[r][m] = __expf(-tt * tt);
      in_s[r][16 + m] = dst_lig_a[(size_t)row*16 + m];
      if (m < 12) {
        float val;
        if (m < 9)       val = v_t[(size_t)row*12 + m];
        else if (m == 9) val = dx / dij;
        else if (m == 10)val = dy / dij;
        else             val = dz / dij;
        v_out[(size_t)row*12 + m] = val;
      }
    }
  }
  __syncthreads();

  // layer 1: 160 -> 128
  float acc[NR];
  const float bb1 = b1[j];
  #pragma unroll
  for (int r = 0; r < NR; ++r) acc[r] = bb1;
  for (int k0 = 0; k0 < 160; k0 += 4) {
    float w0 = W1[(size_t)(k0+0)*128 + j];
    float w1 = W1[(size_t)(k0+1)*128 + j];
    float w2 = W1[(size_t)(k0+2)*128 + j];
    float w3 = W1[(size_t)(k0+3)*128 + j];
    #pragma unroll
    for (int r = 0; r < NR; ++r) {
      float4 a = *reinterpret_cast<const float4*>(&in_s[r][k0]);
      acc[r] = fmaf(a.x, w0, acc[r]);
      acc[r] = fmaf(a.y, w1, acc[r]);
      acc[r] = fmaf(a.z, w2, acc[r]);
      acc[r] = fmaf(a.w, w3, acc[r]);
    }
  }
  #pragma unroll
  for (int r = 0; r < NR; ++r) h_s[r][j] = silu_f(acc[r]);
  __syncthreads();

  // layer 2: 128 -> 128
  const float bb2 = b2[j];
  #pragma unroll
  for (int r = 0; r < NR; ++r) acc[r] = bb2;
  for (int k0 = 0; k0 < 128; k0 += 4) {
    float w0 = W2[(size_t)(k0+0)*128 + j];
    float w1 = W2[(size_t)(k0+1)*128 + j];
    float w2 = W2[(size_t)(k0+2)*128 + j];
    float w3 = W2[(size_t)(k0+3)*128 + j];
    #pragma unroll
    for (int r = 0; r < NR; ++r) {
      float4 a = *reinterpret_cast<const float4*>(&h_s[r][k0]);
      acc[r] = fmaf(a.x, w0, acc[r]);
      acc[r] = fmaf(a.y, w1, acc[r]);
      acc[r] = fmaf(a.z, w2, acc[r]);
      acc[r] = fmaf(a.w, w3, acc[r]);
    }
  }
  #pragma unroll
  for (int r = 0; r < NR; ++r) {
    int row = row0 + r;
    if (row < N)
      node_out[(size_t)row*128 + j] = in_s[r][32 + j] + silu_f(acc[r]);
  }
}

// ---------------- edge kernel: e_out (both halves) ----------------
__global__ __launch_bounds__(256)
void edge_kernel(const float* __restrict__ e_t,
                 const float* __restrict__ x_t,
                 const float* __restrict__ dst_lig_x,
                 const float* __restrict__ dst_lig_e,
                 const int* __restrict__ edge_src,
                 const int* __restrict__ edge_dst,
                 const float* __restrict__ We, const float* __restrict__ be,
                 float* __restrict__ e_out0, float* __restrict__ e_out1,
                 int Eu)
{
  __shared__ float We_s[88*64];     // K padded 85 -> 88, zero-filled (NaN-safe)
  __shared__ float ein[EB][88];     // [e_u 64 | lig_e 5 | d_input 16 | pad 3]
  __shared__ float dd[EB][2];       // [dt, d1] per edge
  const int t = threadIdx.x;
  const int e0 = blockIdx.x * EB;

  // stage We (+ zero pad rows)
  for (int i = t; i < 88*64; i += 256)
    We_s[i] = (i < 85*64) ? We[i] : 0.0f;

  // distances: 32 edges x 2 norms = 64 tasks
  if (t < 64) {
    int el = t >> 1, which = t & 1;
    int e = e0 + el;
    if (e < Eu) {
      int su = edge_src[e], du = edge_dst[e];
      const float* base = which ? dst_lig_x : x_t;
      float u0 = base[su*3+0] - base[du*3+0];
      float u1 = base[su*3+1] - base[du*3+1];
      float u2 = base[su*3+2] - base[du*3+2];
      dd[el][which] = sqrtf(fmaxf(u0*u0 + u1*u1 + u2*u2, 1e-8f));
    }
  }

  // e_u rows (coalesced)
  {
    const int g = t >> 6, c = t & 63;
    #pragma unroll
    for (int p = 0; p < 8; ++p) {
      int el = p*4 + g;
      int e = e0 + el;
      if (e < Eu) ein[el][c] = e_t[(size_t)e*64 + c];
    }
  }
  // dst_lig_e
  if (t < EB*5) {
    int el = t / 5, q = t % 5;
    int e = e0 + el;
    if (e < Eu) ein[el][64+q] = dst_lig_e[(size_t)e*5 + q];
  }
  // zero pad cols 85..87
  if (t < EB*3) {
    int el = t / 3, p = t % 3;
    ein[el][85+p] = 0.0f;
  }
  __syncthreads();

  // d_input = rbf(d1) - rbf(dt): 32 edges x 16 = 512 tasks, 2 passes
  #pragma unroll
  for (int p = 0; p < 2; ++p) {
    int el = p*16 + (t >> 4);
    int m  = t & 15;
    int e  = e0 + el;
    if (e < Eu) {
      float dt_ = dd[el][0], d1_ = dd[el][1];
      float mu = 0.66666667f * (float)m;
      float a1 = (d1_ - mu) * 1.6f;
      float a2 = (dt_ - mu) * 1.6f;
      ein[el][69+m] = __expf(-a1*a1) - __expf(-a2*a2);
    }
  }
  __syncthreads();

  // GEMM: each lane = one column j, 8 edges per lane
  const int g = t >> 6, j = t & 63;
  float acc[8];
  const float bbe = be[j];
  #pragma unroll
  for (int e = 0; e < 8; ++e) acc[e] = bbe;
  for (int k0 = 0; k0 < 88; k0 += 4) {
    float w0 = We_s[(k0+0)*64 + j];
    float w1 = We_s[(k0+1)*64 + j];
    float w2 = We_s[(k0+2)*64 + j];
    float w3 = We_s[(k0+3)*64 + j];
    #pragma unroll
    for (int e = 0; e < 8; ++e) {
      float4 a = *reinterpret_cast<const float4*>(&ein[g*8+e][k0]);
      acc[e] = fmaf(a.x, w0, acc[e]);
      acc[e] = fmaf(a.y, w1, acc[e]);
      acc[e] = fmaf(a.z, w2, acc[e]);
      acc[e] = fmaf(a.w, w3, acc[e]);
    }
  }
  #pragma unroll
  for (int e = 0; e < 8; ++e) {
    int el = g*8 + e;
    size_t eidx = (size_t)e0 + el;
    if ((int)eidx < Eu) {
      float feat = ein[el][j] + silu_f(acc[e]);
      e_out0[eidx*64 + j] = feat;
      e_out1[eidx*64 + j] = feat;
    }
  }
}

extern "C" void kernel_launch(void* const* d_in, const int* in_sizes, int n_in,
                              void* d_out, int out_size, void* d_ws, size_t ws_size,
                              hipStream_t stream) {
  const float* s_t       = (const float*)d_in[0];
  const float* x_t       = (const float*)d_in[1];
  const float* v_t       = (const float*)d_in[2];
  const float* e_t       = (const float*)d_in[3];
  const float* dst_lig_x = (const float*)d_in[4];
  const float* dst_lig_a = (const float*)d_in[5];
  const float* dst_lig_e = (const float*)d_in[6];
  const int*   edge_src  = (const int*)d_in[7];
  const int*   edge_dst  = (const int*)d_in[8];
  const float* W1        = (const float*)d_in[9];
  const float* b1        = (const float*)d_in[10];
  const float* W2        = (const float*)d_in[11];
  const float* b2        = (const float*)d_in[12];
  const float* We        = (const float*)d_in[13];
  const float* be        = (const float*)d_in[14];

  const int N  = in_sizes[0] / 128;       // 100000
  const int Eu = in_sizes[3] / 128;       // e_t = (2*Eu, 64) -> 800000

  float* out      = (float*)d_out;
  float* node_out = out;
  float* v_out    = out + (size_t)N * 128;
  float* e_out0   = v_out + (size_t)N * 12;
  float* e_out1   = e_out0 + (size_t)Eu * 64;

  node_kernel<<<(N + NR - 1) / NR, 128, 0, stream>>>(
      s_t, x_t, v_t, dst_lig_x, dst_lig_a, W1, b1, W2, b2,
      node_out, v_out, N);

  edge_kernel<<<(Eu + EB - 1) / EB, 256, 0, stream>>>(
      e_t, x_t, dst_lig_x, dst_lig_e, edge_src, edge_dst, We, be,
      e_out0, e_out1, Eu);
}